// Round 1
// baseline (1294.328 us; speedup 1.0000x reference)
//
#include <hip/hip_runtime.h>

// Problem constants (fixed by setup_inputs)
#define BB 4
#define CC 64      // feature channels
#define KK 16      // neighbors
#define NN 16384   // points
#define WO 16      // weightnet out channels
#define NT 64      // n-points per block

// ---------------------------------------------------------------------------
// Fused: weightnet (3->16 relu) + aggregation (C x K @ K x 16) + linear
// (1024 -> 64) + per-channel sum/sumsq partials for BatchNorm.
// One block = 64 consecutive n for one batch b. 256 threads = 4 waves.
// Wave q owns weightnet channels o in {4q..4q+3} (stage A) and output
// channels oc in {16q..16q+15} (stage B).
// ---------------------------------------------------------------------------
__global__ __launch_bounds__(256, 2)
void fused_main(const float* __restrict__ points,
                const float* __restrict__ coordinate,
                const float* __restrict__ w1,
                const float* __restrict__ b1,
                const float* __restrict__ lin_w,
                const float* __restrict__ lin_b,
                float* __restrict__ y_out,   // [B][C][N] pre-BN values
                float* __restrict__ stats)   // [0..63]=sum, [64..127]=sumsq
{
    __shared__ float s_p[4][KK][NT];      // 16 KB: points tile for 4 c's
    __shared__ float s_agg[4][4][NT][4];  // 16 KB: [c][oq][n][j], o = 4*oq+j

    const int t = threadIdx.x;
    const int n = t & 63;
    const int q = __builtin_amdgcn_readfirstlane(t >> 6);  // wave id, SGPR

    const int bid = blockIdx.x;
    const int b  = bid >> 8;            // / (NN/NT) = / 256
    const int n0 = (bid & 255) * NT;

    // ---- weightnet into registers: wreg[j][k] = relu(b1[o] + w1[o,:]·coord[:,k,n])
    float wreg[4][KK];
    {
        const float* coordB = coordinate + (size_t)b * 3 * KK * NN + n0 + n;
        float c0[KK], c1[KK], c2[KK];
        #pragma unroll
        for (int k = 0; k < KK; ++k) {
            c0[k] = coordB[(0 * KK + k) * NN];
            c1[k] = coordB[(1 * KK + k) * NN];
            c2[k] = coordB[(2 * KK + k) * NN];
        }
        #pragma unroll
        for (int j = 0; j < 4; ++j) {
            const int o = 4 * q + j;
            const float w1x = w1[o * 3 + 0];
            const float w1y = w1[o * 3 + 1];
            const float w1z = w1[o * 3 + 2];
            const float bo  = b1[o];
            #pragma unroll
            for (int k = 0; k < KK; ++k) {
                float v = fmaf(w1x, c0[k], fmaf(w1y, c1[k], fmaf(w1z, c2[k], bo)));
                wreg[j][k] = fmaxf(v, 0.0f);
            }
        }
    }

    float y[16];
    #pragma unroll
    for (int j = 0; j < 16; ++j) y[j] = 0.0f;

    const float* pBase = points + (size_t)b * CC * KK * NN + n0;

    for (int c4 = 0; c4 < CC; c4 += 4) {
        __syncthreads();  // previous iter's s_p/s_agg consumers are done
        // ---- stage 0: cooperative load of points tiles for c4..c4+3
        {
            const int k   = t >> 4;          // 0..15
            const int nn4 = (t & 15) * 4;    // 0,4,...,60
            #pragma unroll
            for (int cc = 0; cc < 4; ++cc) {
                const float4 v =
                    *(const float4*)(pBase + ((size_t)(c4 + cc) * KK + k) * NN + nn4);
                *(float4*)&s_p[cc][k][nn4] = v;
            }
        }
        __syncthreads();
        // ---- stage A: agg[o][n] = sum_k p[k][n] * w[o][k][n]   (o = 4q+j)
        #pragma unroll
        for (int cc = 0; cc < 4; ++cc) {
            float a0 = 0, a1 = 0, a2 = 0, a3 = 0;
            #pragma unroll
            for (int k = 0; k < KK; ++k) {
                const float pv = s_p[cc][k][n];
                a0 = fmaf(pv, wreg[0][k], a0);
                a1 = fmaf(pv, wreg[1][k], a1);
                a2 = fmaf(pv, wreg[2][k], a2);
                a3 = fmaf(pv, wreg[3][k], a3);
            }
            *(float4*)&s_agg[cc][q][n][0] = make_float4(a0, a1, a2, a3);
        }
        __syncthreads();
        // ---- stage B: y[oc][n] += sum_o LW[oc][c*16+o] * agg[o][n]
        #pragma unroll
        for (int cc = 0; cc < 4; ++cc) {
            float av[16];
            #pragma unroll
            for (int oq = 0; oq < 4; ++oq) {
                const float4 v = *(const float4*)&s_agg[cc][oq][n][0];
                av[4 * oq + 0] = v.x; av[4 * oq + 1] = v.y;
                av[4 * oq + 2] = v.z; av[4 * oq + 3] = v.w;
            }
            const int c = c4 + cc;
            #pragma unroll
            for (int j = 0; j < 16; ++j) {
                // (16q+j) is wave-uniform -> scalar loads of lin_w row chunk
                const float* lwp = lin_w + (size_t)(16 * q + j) * 1024 + c * 16;
                float acc = y[j];
                #pragma unroll
                for (int o = 0; o < 16; ++o) acc = fmaf(lwp[o], av[o], acc);
                y[j] = acc;
            }
        }
    }

    // ---- bias, store pre-BN, per-channel partial sums
    #pragma unroll
    for (int j = 0; j < 16; ++j) y[j] += lin_b[16 * q + j];

    float* yo = y_out + (size_t)b * CC * NN + n0 + n;
    #pragma unroll
    for (int j = 0; j < 16; ++j) yo[(size_t)(16 * q + j) * NN] = y[j];

    #pragma unroll
    for (int j = 0; j < 16; ++j) {
        float s  = y[j];
        float ss = y[j] * y[j];
        #pragma unroll
        for (int m = 1; m < 64; m <<= 1) {
            s  += __shfl_xor(s, m);
            ss += __shfl_xor(ss, m);
        }
        if (n == 0) {
            atomicAdd(&stats[16 * q + j], s);
            atomicAdd(&stats[64 + 16 * q + j], ss);
        }
    }
}

// ---------------------------------------------------------------------------
// Stats -> per-channel affine (a, b): out = relu(a*y + b)
// ---------------------------------------------------------------------------
__global__ void bn_stats(const float* __restrict__ stats,
                         const float* __restrict__ gamma,
                         const float* __restrict__ beta,
                         float* __restrict__ ab)
{
    const int ch = threadIdx.x;
    const float inv = 1.0f / (float)(BB * NN);
    const float mean = stats[ch] * inv;
    const float var  = stats[64 + ch] * inv - mean * mean;
    const float rstd = rsqrtf(var + 1e-5f);
    const float a = gamma[ch] * rstd;
    ab[ch]      = a;
    ab[64 + ch] = beta[ch] - mean * a;
}

// ---------------------------------------------------------------------------
// In-place normalize + relu over [B][C][N], vectorized float4
// ---------------------------------------------------------------------------
__global__ __launch_bounds__(256)
void bn_apply(float* __restrict__ y, const float* __restrict__ ab)
{
    const size_t i = (size_t)blockIdx.x * 256 + threadIdx.x;  // float4 index
    float4* p = (float4*)y;
    float4 v = p[i];
    const int ch = (int)((i * 4) >> 14) & 63;  // (elem / N) % C
    const float a = ab[ch], bb = ab[64 + ch];
    v.x = fmaxf(fmaf(a, v.x, bb), 0.0f);
    v.y = fmaxf(fmaf(a, v.y, bb), 0.0f);
    v.z = fmaxf(fmaf(a, v.z, bb), 0.0f);
    v.w = fmaxf(fmaf(a, v.w, bb), 0.0f);
    p[i] = v;
}

extern "C" void kernel_launch(void* const* d_in, const int* in_sizes, int n_in,
                              void* d_out, int out_size, void* d_ws, size_t ws_size,
                              hipStream_t stream)
{
    const float* xyz        = (const float*)d_in[0];
    const float* points     = (const float*)d_in[1];
    const float* coordinate = (const float*)d_in[2];
    const float* w1         = (const float*)d_in[3];
    const float* b1         = (const float*)d_in[4];
    const float* lin_w      = (const float*)d_in[5];
    const float* lin_b      = (const float*)d_in[6];
    const float* gamma      = (const float*)d_in[7];
    const float* beta       = (const float*)d_in[8];

    float* out = (float*)d_out;
    float* ws  = (float*)d_ws;

    const size_t xyz_elems = (size_t)BB * NN * 3;  // 196608, output 0 passthrough

    hipMemcpyAsync(out, xyz, xyz_elems * sizeof(float),
                   hipMemcpyDeviceToDevice, stream);
    hipMemsetAsync(ws, 0, 128 * sizeof(float), stream);  // zero sum/sumsq

    float* y_out = out + xyz_elems;  // [B][C][N]

    fused_main<<<BB * (NN / NT), 256, 0, stream>>>(
        points, coordinate, w1, b1, lin_w, lin_b, y_out, ws);
    bn_stats<<<1, 64, 0, stream>>>(ws, gamma, beta, ws + 128);
    bn_apply<<<(BB * CC * NN) / 4 / 256, 256, 0, stream>>>(y_out, ws + 128);
}

// Round 2
// 488.493 us; speedup vs baseline: 2.6496x; 2.6496x over previous
//
#include <hip/hip_runtime.h>

// Problem constants (fixed by setup_inputs)
#define BB 4
#define CC 64      // feature channels
#define KK 16      // neighbors
#define NN 16384   // points
#define NT 64      // points per block
#define CH 8       // feature channels per chunk
#define KS 128     // linear-K slice per chunk = CH*16

typedef __attribute__((ext_vector_type(8))) short short8;   // 8 bf16 = 4 VGPRs
typedef __attribute__((ext_vector_type(4))) float floatx4;  // MFMA C/D

__device__ __forceinline__ unsigned short f2bf(float x) {   // RTNE f32->bf16
    unsigned u = __builtin_bit_cast(unsigned, x);
    u += 0x7FFFu + ((u >> 16) & 1u);
    return (unsigned short)(u >> 16);
}
__device__ __forceinline__ float bflo(unsigned u) {         // low bf16 of word
    return __builtin_bit_cast(float, u << 16);
}
__device__ __forceinline__ float bfhi(unsigned u) {         // high bf16 of word
    return __builtin_bit_cast(float, u & 0xFFFF0000u);
}

// ---------------------------------------------------------------------------
// Fused: weightnet (3->16 relu, registers) + aggregation (VALU, ->LDS bf16)
// + linear 1024->64 via bf16 MFMA 16x16x32. One block = 64 points of one
// batch. 256 threads = 4 waves; wave q owns weightnet o in {4q..4q+3} and
// M-tile q (points 16q..16q+15) in the GEMM.
// lin_b is intentionally dropped: training-mode BN cancels per-channel shifts.
// ---------------------------------------------------------------------------
__global__ __launch_bounds__(256, 2)
void fused_main(const float* __restrict__ points,
                const float* __restrict__ coordinate,
                const float* __restrict__ w1,
                const float* __restrict__ b1,
                const float* __restrict__ lin_w,
                float* __restrict__ y_out)   // [B][C][N] pre-BN
{
    // s_p: points chunk, [c_l][n][k] with k contiguous; 24 = 16 + 8 pad
    // (48 B row stride -> 8 distinct 4-bank groups for the wave, min phases)
    __shared__ __align__(16) unsigned short s_p[CH][NT][24];      // 24 KB
    // s_a: agg in MFMA-A layout [point n][k'], row pad +8 (272 B stride)
    __shared__ __align__(16) unsigned short s_a[NT][KS + 8];      // 17 KB
    // s_w: lin_w K-slice [oc][k'], same pad
    __shared__ __align__(16) unsigned short s_w[CC][KS + 8];      // 17 KB

    const int t    = threadIdx.x;
    const int lane = t & 63;
    const int q    = __builtin_amdgcn_readfirstlane(t >> 6);
    const int r    = lane & 15;   // MFMA row-in-fragment / col-in-D
    const int s    = lane >> 4;   // MFMA quad

    const int bid = blockIdx.x;
    const int b   = bid >> 8;             // 256 blocks per batch
    const int n0  = (bid & 255) * NT;

    // ---- weightnet into registers: wreg[j][k] = relu(b1[o] + w1[o]·coord)
    float wreg[4][KK];
    {
        const float* coordB = coordinate + (size_t)b * 3 * KK * NN + n0 + lane;
        float c0[KK], c1[KK], c2[KK];
        #pragma unroll
        for (int k = 0; k < KK; ++k) {
            c0[k] = coordB[(0 * KK + k) * NN];
            c1[k] = coordB[(1 * KK + k) * NN];
            c2[k] = coordB[(2 * KK + k) * NN];
        }
        #pragma unroll
        for (int j = 0; j < 4; ++j) {
            const int o = 4 * q + j;
            const float w1x = w1[o * 3 + 0];
            const float w1y = w1[o * 3 + 1];
            const float w1z = w1[o * 3 + 2];
            const float bo  = b1[o];
            #pragma unroll
            for (int k = 0; k < KK; ++k) {
                float v = fmaf(w1x, c0[k], fmaf(w1y, c1[k], fmaf(w1z, c2[k], bo)));
                wreg[j][k] = fmaxf(v, 0.0f);
            }
        }
    }

    floatx4 acc[4];
    #pragma unroll
    for (int nt = 0; nt < 4; ++nt) acc[nt] = (floatx4){0.f, 0.f, 0.f, 0.f};

    const float* pB = points + (size_t)b * CC * KK * NN + n0;

    for (int c8 = 0; c8 < CC; c8 += CH) {
        __syncthreads();  // previous chunk's consumers done before overwrite

        // ---- phase 1a: stage points chunk fp32->bf16, transposed to [c][n][k]
        #pragma unroll
        for (int w = 0; w < 8; ++w) {
            const int idx = w * 256 + t;            // 0..2047
            const int c_l = idx >> 8;               // 0..7
            const int k   = (idx >> 4) & 15;        // 0..15
            const int n4  = (idx & 15) * 4;         // 0..60
            const float4 v =
                *(const float4*)(pB + ((size_t)(c8 + c_l) * KK + k) * NN + n4);
            s_p[c_l][n4 + 0][k] = f2bf(v.x);
            s_p[c_l][n4 + 1][k] = f2bf(v.y);
            s_p[c_l][n4 + 2][k] = f2bf(v.z);
            s_p[c_l][n4 + 3][k] = f2bf(v.w);
        }
        // ---- phase 1b: stage lin_w slice [oc][k'=0..127] fp32->bf16
        #pragma unroll
        for (int w = 0; w < 8; ++w) {
            const int idx = w * 256 + t;            // 0..2047
            const int oc  = idx >> 5;               // 0..63
            const int k4  = (idx & 31) * 4;         // 0..124
            const float4 v =
                *(const float4*)(lin_w + (size_t)oc * 1024 + c8 * 16 + k4);
            ushort4 pk;
            pk.x = f2bf(v.x); pk.y = f2bf(v.y); pk.z = f2bf(v.z); pk.w = f2bf(v.w);
            *(ushort4*)&s_w[oc][k4] = pk;
        }
        __syncthreads();

        // ---- phase 2: aggregation. agg[n][c_l*16 + o] = sum_k p[c][k][n]*w[o][k][n]
        #pragma unroll
        for (int c_l = 0; c_l < CH; ++c_l) {
            const uint4 u0 = *(const uint4*)&s_p[c_l][lane][0];
            const uint4 u1 = *(const uint4*)&s_p[c_l][lane][8];
            float p16[16];
            p16[0]  = bflo(u0.x); p16[1]  = bfhi(u0.x);
            p16[2]  = bflo(u0.y); p16[3]  = bfhi(u0.y);
            p16[4]  = bflo(u0.z); p16[5]  = bfhi(u0.z);
            p16[6]  = bflo(u0.w); p16[7]  = bfhi(u0.w);
            p16[8]  = bflo(u1.x); p16[9]  = bfhi(u1.x);
            p16[10] = bflo(u1.y); p16[11] = bfhi(u1.y);
            p16[12] = bflo(u1.z); p16[13] = bfhi(u1.z);
            p16[14] = bflo(u1.w); p16[15] = bfhi(u1.w);
            float a4[4];
            #pragma unroll
            for (int j = 0; j < 4; ++j) {
                float a = 0.f;
                #pragma unroll
                for (int k = 0; k < KK; ++k) a = fmaf(p16[k], wreg[j][k], a);
                a4[j] = a;
            }
            ushort4 pk;
            pk.x = f2bf(a4[0]); pk.y = f2bf(a4[1]);
            pk.z = f2bf(a4[2]); pk.w = f2bf(a4[3]);
            *(ushort4*)&s_a[lane][c_l * 16 + 4 * q] = pk;  // 8B-aligned
        }
        __syncthreads();

        // ---- phase 3: MFMA. Wave q: M-tile q, all 4 N-tiles, K=128 slice.
        #pragma unroll
        for (int kk = 0; kk < 4; ++kk) {
            const short8 af = *(const short8*)&s_a[16 * q + r][kk * 32 + s * 8];
            #pragma unroll
            for (int nt = 0; nt < 4; ++nt) {
                const short8 bf = *(const short8*)&s_w[nt * 16 + r][kk * 32 + s * 8];
                acc[nt] = __builtin_amdgcn_mfma_f32_16x16x32_bf16(af, bf, acc[nt], 0, 0, 0);
            }
        }
    }

    // ---- epilogue: D layout col=lane&15 (oc), row=quad*4+reg (point)
    float* yB = y_out + (size_t)b * CC * NN + n0;
    #pragma unroll
    for (int nt = 0; nt < 4; ++nt) {
        const int oc = nt * 16 + r;
        const float4 v = make_float4(acc[nt][0], acc[nt][1], acc[nt][2], acc[nt][3]);
        *(float4*)(yB + (size_t)oc * NN + 16 * q + 4 * s) = v;
    }
}

// ---------------------------------------------------------------------------
// Per-channel batch stats over y [B][C][N] -> affine (a, b). One block per ch.
// ---------------------------------------------------------------------------
__global__ __launch_bounds__(256)
void bn_reduce(const float* __restrict__ y, const float* __restrict__ gamma,
               const float* __restrict__ beta, float* __restrict__ ab)
{
    const int ch = blockIdx.x;
    const int t  = threadIdx.x;
    float s = 0.f, ss = 0.f;
    for (int b = 0; b < BB; ++b) {
        const float4* p = (const float4*)(y + ((size_t)b * CC + ch) * NN);
        for (int i = t; i < NN / 4; i += 256) {
            const float4 v = p[i];
            s  += v.x + v.y + v.z + v.w;
            ss += v.x * v.x + v.y * v.y + v.z * v.z + v.w * v.w;
        }
    }
    #pragma unroll
    for (int m = 1; m < 64; m <<= 1) {
        s  += __shfl_xor(s, m);
        ss += __shfl_xor(ss, m);
    }
    __shared__ float rs[4], rss[4];
    if ((t & 63) == 0) { rs[t >> 6] = s; rss[t >> 6] = ss; }
    __syncthreads();
    if (t == 0) {
        const float S  = rs[0] + rs[1] + rs[2] + rs[3];
        const float SS = rss[0] + rss[1] + rss[2] + rss[3];
        const float inv  = 1.0f / (float)(BB * NN);
        const float mean = S * inv;
        const float var  = SS * inv - mean * mean;
        const float a    = gamma[ch] * rsqrtf(var + 1e-5f);
        ab[ch]      = a;
        ab[CC + ch] = beta[ch] - mean * a;
    }
}

// ---------------------------------------------------------------------------
// In-place normalize + relu over [B][C][N], float4
// ---------------------------------------------------------------------------
__global__ __launch_bounds__(256)
void bn_apply(float* __restrict__ y, const float* __restrict__ ab)
{
    const size_t i = (size_t)blockIdx.x * 256 + threadIdx.x;  // float4 index
    float4* p = (float4*)y;
    float4 v = p[i];
    const int ch = (int)((i * 4) >> 14) & 63;  // (elem / N) % C
    const float a = ab[ch], bb = ab[CC + ch];
    v.x = fmaxf(fmaf(a, v.x, bb), 0.0f);
    v.y = fmaxf(fmaf(a, v.y, bb), 0.0f);
    v.z = fmaxf(fmaf(a, v.z, bb), 0.0f);
    v.w = fmaxf(fmaf(a, v.w, bb), 0.0f);
    p[i] = v;
}

extern "C" void kernel_launch(void* const* d_in, const int* in_sizes, int n_in,
                              void* d_out, int out_size, void* d_ws, size_t ws_size,
                              hipStream_t stream)
{
    const float* xyz        = (const float*)d_in[0];
    const float* points     = (const float*)d_in[1];
    const float* coordinate = (const float*)d_in[2];
    const float* w1         = (const float*)d_in[3];
    const float* b1         = (const float*)d_in[4];
    const float* lin_w      = (const float*)d_in[5];
    // d_in[6] = lin_b: unused — training-mode BN cancels per-channel shifts
    const float* gamma      = (const float*)d_in[7];
    const float* beta       = (const float*)d_in[8];

    float* out = (float*)d_out;
    float* ws  = (float*)d_ws;   // ab[] affine params (128 floats)

    const size_t xyz_elems = (size_t)BB * NN * 3;  // output 0 passthrough

    hipMemcpyAsync(out, xyz, xyz_elems * sizeof(float),
                   hipMemcpyDeviceToDevice, stream);

    float* y_out = out + xyz_elems;  // [B][C][N]

    fused_main<<<BB * (NN / NT), 256, 0, stream>>>(
        points, coordinate, w1, b1, lin_w, y_out);
    bn_reduce<<<CC, 256, 0, stream>>>(y_out, gamma, beta, ws);
    bn_apply<<<(BB * CC * NN) / 4 / 256, 256, 0, stream>>>(y_out, ws);
}

// Round 4
// 458.662 us; speedup vs baseline: 2.8220x; 1.0650x over previous
//
#include <hip/hip_runtime.h>

// Problem constants (fixed by setup_inputs)
#define BB 4
#define CC 64      // feature channels
#define KK 16      // neighbors
#define NN 16384   // points
#define NT 64      // points per block
#define CH 8       // feature channels per chunk
#define NCH 8      // chunks

typedef __attribute__((ext_vector_type(8))) short short8;     // 8 bf16 (MFMA A/B)
typedef __attribute__((ext_vector_type(4))) float floatx4;    // MFMA C/D
typedef __attribute__((ext_vector_type(2))) _Float16 half2v;  // packed f16 pair

__device__ __forceinline__ unsigned short f2bf_rtne(float x) {  // RTNE f32->bf16
    unsigned u = __builtin_bit_cast(unsigned, x);
    u += 0x7FFFu + ((u >> 16) & 1u);
    return (unsigned short)(u >> 16);
}

// pack two f32 into bf16x2 (round-half-up via +0x8000, then v_perm byte-select)
__device__ __forceinline__ unsigned pack_bf16x2(float lo, float hi) {
    unsigned a = __builtin_bit_cast(unsigned, lo) + 0x8000u;
    unsigned b = __builtin_bit_cast(unsigned, hi) + 0x8000u;
    return __builtin_amdgcn_perm(b, a, 0x07060302u);  // {b.hi16, a.hi16}
}

// cvt_pkrtz returns __fp16x2; bit_cast to _Float16x2 for fdot2
__device__ __forceinline__ half2v cvt2h(float a, float b) {
    return __builtin_bit_cast(half2v, __builtin_amdgcn_cvt_pkrtz(a, b));
}

#if __has_builtin(__builtin_amdgcn_fdot2)
#define DOT2(a, b, c) __builtin_amdgcn_fdot2((a), (b), (c), false)
#else
__device__ __forceinline__ float dot2_fb(half2v a, half2v b, float c) {
    return fmaf((float)a[0], (float)b[0], fmaf((float)a[1], (float)b[1], c));
}
#define DOT2(a, b, c) dot2_fb((a), (b), (c))
#endif

// ---------------------------------------------------------------------------
// One-time: repack lin_w (f32 [64][1024]) into bf16 MFMA B-fragments in the
// exact per-wave load order: [chunk ci][kk][nt][lane]{8 bf16}. 128 KB total.
// B-frag (16x16x32): lane (r,s) holds B[col=nt*16+r][k=kk*32+s*8+j].
// ---------------------------------------------------------------------------
__global__ __launch_bounds__(256)
void prep_bfrag(const float* __restrict__ lin_w, unsigned short* __restrict__ bfrag)
{
    const int tid  = blockIdx.x * 256 + threadIdx.x;  // 0..8191
    const int lane = tid & 63;
    const int g    = tid >> 6;            // 0..127 = (ci,kk,nt)
    const int ci   = g >> 4;
    const int kk   = (g >> 2) & 3;
    const int nt   = g & 3;
    const int r    = lane & 15;
    const int sq   = lane >> 4;

    const float* src = lin_w + (size_t)(nt * 16 + r) * 1024 + ci * 128 + kk * 32 + sq * 8;
    unsigned short v[8];
    #pragma unroll
    for (int j = 0; j < 8; ++j) v[j] = f2bf_rtne(src[j]);
    *(uint4*)(bfrag + ((size_t)g * 64 + lane) * 8) = *(const uint4*)v;
}

// ---------------------------------------------------------------------------
// Fused: weightnet (3->16 relu, f16-pair registers) + aggregation (v_dot2
// straight from global points — coalesced 256B/wave dword reads, no staging)
// + linear 1024->64 via bf16 MFMA with pre-packed global B-fragments.
// One block = 64 points. 4 waves; wave q: weightnet o in {4q..4q+3}, GEMM
// M-tile q (points 16q..16q+15). lin_b dropped: training-mode BN cancels it.
// Only LDS: s_a round-trip to reshape agg (lane=n) -> MFMA A-layout.
// ---------------------------------------------------------------------------
__global__ __launch_bounds__(256, 4)
void fused_main(const float* __restrict__ points,
                const float* __restrict__ coordinate,
                const float* __restrict__ w1,
                const float* __restrict__ b1,
                const unsigned short* __restrict__ bfrag,
                float* __restrict__ y_out)   // [B][C][N] pre-BN
{
    // agg in MFMA-A layout [point n][k'], row stride 136 shorts (272 B,
    // 16B-aligned for b128 A-reads)
    __shared__ __align__(16) unsigned short s_a[NT][136];   // 17.4 KB

    const int t    = threadIdx.x;
    const int lane = t & 63;
    const int q    = __builtin_amdgcn_readfirstlane(t >> 6);
    const int r    = lane & 15;
    const int sq   = lane >> 4;

    const int bid = blockIdx.x;
    const int b   = bid >> 8;             // 256 blocks per batch
    const int n0  = (bid & 255) * NT;

    // ---- weightnet into f16-pair registers: wh[j][kp] = relu(...) pairs over k
    half2v wh[4][8];
    {
        const float* coordB = coordinate + (size_t)b * 3 * KK * NN + n0 + lane;
        float c0[KK], c1[KK], c2[KK];
        #pragma unroll
        for (int k = 0; k < KK; ++k) {
            c0[k] = coordB[(0 * KK + k) * NN];
            c1[k] = coordB[(1 * KK + k) * NN];
            c2[k] = coordB[(2 * KK + k) * NN];
        }
        #pragma unroll
        for (int j = 0; j < 4; ++j) {
            const int o = 4 * q + j;
            const float w1x = w1[o * 3 + 0];
            const float w1y = w1[o * 3 + 1];
            const float w1z = w1[o * 3 + 2];
            const float bo  = b1[o];
            #pragma unroll
            for (int kp = 0; kp < 8; ++kp) {
                float v0 = fmaf(w1x, c0[2 * kp],     fmaf(w1y, c1[2 * kp],     fmaf(w1z, c2[2 * kp],     bo)));
                float v1 = fmaf(w1x, c0[2 * kp + 1], fmaf(w1y, c1[2 * kp + 1], fmaf(w1z, c2[2 * kp + 1], bo)));
                wh[j][kp] = cvt2h(fmaxf(v0, 0.0f), fmaxf(v1, 0.0f));
            }
        }
    }

    floatx4 acc[4];
    #pragma unroll
    for (int nt = 0; nt < 4; ++nt) acc[nt] = (floatx4){0.f, 0.f, 0.f, 0.f};

    const float* pB = points + (size_t)b * CC * KK * NN + n0 + lane;

    for (int ci = 0; ci < NCH; ++ci) {
        // ---- aggregation straight from global (lane = point n)
        uint2 packA[CH];
        #pragma unroll
        for (int cl = 0; cl < CH; ++cl) {
            const float* pc = pB + (size_t)(ci * CH + cl) * KK * NN;
            float pv[KK];
            #pragma unroll
            for (int k = 0; k < KK; ++k) pv[k] = pc[(size_t)k * NN];  // 256B/wave, coalesced
            half2v ph[8];
            #pragma unroll
            for (int kp = 0; kp < 8; ++kp)
                ph[kp] = cvt2h(pv[2 * kp], pv[2 * kp + 1]);
            float a4[4];
            #pragma unroll
            for (int j = 0; j < 4; ++j) {
                float a = 0.f;
                #pragma unroll
                for (int kp = 0; kp < 8; ++kp) a = DOT2(ph[kp], wh[j][kp], a);
                a4[j] = a;
            }
            packA[cl].x = pack_bf16x2(a4[0], a4[1]);
            packA[cl].y = pack_bf16x2(a4[2], a4[3]);
        }

        __syncthreads();  // previous chunk's MFMA A-reads complete
        #pragma unroll
        for (int cl = 0; cl < CH; ++cl)
            *(uint2*)&s_a[lane][cl * 16 + 4 * q] = packA[cl];
        __syncthreads();  // s_a visible to all waves

        // ---- MFMA: wave q = M-tile q, 4 N-tiles, K=128 slice; B from global
        #pragma unroll
        for (int kk = 0; kk < 4; ++kk) {
            const short8 af = *(const short8*)&s_a[16 * q + r][kk * 32 + sq * 8];
            #pragma unroll
            for (int nt = 0; nt < 4; ++nt) {
                const short8 bf = *(const short8*)
                    (bfrag + ((((size_t)ci * 4 + kk) * 4 + nt) * 64 + lane) * 8);
                acc[nt] = __builtin_amdgcn_mfma_f32_16x16x32_bf16(af, bf, acc[nt], 0, 0, 0);
            }
        }
    }

    // ---- epilogue: D layout col=lane&15 (oc), row=quad*4+reg (point)
    float* yB = y_out + (size_t)b * CC * NN + n0;
    #pragma unroll
    for (int nt = 0; nt < 4; ++nt) {
        const int oc = nt * 16 + r;
        const float4 v = make_float4(acc[nt][0], acc[nt][1], acc[nt][2], acc[nt][3]);
        *(float4*)(yB + (size_t)oc * NN + 16 * q + 4 * sq) = v;
    }
}

// ---------------------------------------------------------------------------
// Partial batch stats: one block per (b, ch); deterministic.
// ---------------------------------------------------------------------------
__global__ __launch_bounds__(256)
void bn_reduce(const float* __restrict__ y, float* __restrict__ part)
{
    const int ch = blockIdx.x & 63;
    const int b  = blockIdx.x >> 6;
    const int t  = threadIdx.x;
    const float4* p = (const float4*)(y + ((size_t)b * CC + ch) * NN);
    float s = 0.f, ss = 0.f;
    for (int i = t; i < NN / 4; i += 256) {
        const float4 v = p[i];
        s  += v.x + v.y + v.z + v.w;
        ss += v.x * v.x + v.y * v.y + v.z * v.z + v.w * v.w;
    }
    #pragma unroll
    for (int m = 1; m < 64; m <<= 1) {
        s  += __shfl_xor(s, m);
        ss += __shfl_xor(ss, m);
    }
    __shared__ float rs[4], rss[4];
    if ((t & 63) == 0) { rs[t >> 6] = s; rss[t >> 6] = ss; }
    __syncthreads();
    if (t == 0) {
        part[blockIdx.x]       = rs[0] + rs[1] + rs[2] + rs[3];
        part[256 + blockIdx.x] = rss[0] + rss[1] + rss[2] + rss[3];
    }
}

__global__ void bn_stats(const float* __restrict__ part,
                         const float* __restrict__ gamma,
                         const float* __restrict__ beta,
                         float* __restrict__ ab)
{
    const int ch = threadIdx.x;
    float S = 0.f, SS = 0.f;
    #pragma unroll
    for (int b = 0; b < BB; ++b) {
        S  += part[b * 64 + ch];
        SS += part[256 + b * 64 + ch];
    }
    const float inv  = 1.0f / (float)(BB * NN);
    const float mean = S * inv;
    const float var  = SS * inv - mean * mean;
    const float a    = gamma[ch] * rsqrtf(var + 1e-5f);
    ab[ch]      = a;
    ab[CC + ch] = beta[ch] - mean * a;
}

__global__ __launch_bounds__(256)
void bn_apply(float* __restrict__ y, const float* __restrict__ ab)
{
    const size_t i = (size_t)blockIdx.x * 256 + threadIdx.x;  // float4 index
    float4* p = (float4*)y;
    float4 v = p[i];
    const int ch = (int)((i * 4) >> 14) & 63;  // (elem / N) % C
    const float a = ab[ch], bb = ab[CC + ch];
    v.x = fmaxf(fmaf(a, v.x, bb), 0.0f);
    v.y = fmaxf(fmaf(a, v.y, bb), 0.0f);
    v.z = fmaxf(fmaf(a, v.z, bb), 0.0f);
    v.w = fmaxf(fmaf(a, v.w, bb), 0.0f);
    p[i] = v;
}

extern "C" void kernel_launch(void* const* d_in, const int* in_sizes, int n_in,
                              void* d_out, int out_size, void* d_ws, size_t ws_size,
                              hipStream_t stream)
{
    const float* xyz        = (const float*)d_in[0];
    const float* points     = (const float*)d_in[1];
    const float* coordinate = (const float*)d_in[2];
    const float* w1         = (const float*)d_in[3];
    const float* b1         = (const float*)d_in[4];
    const float* lin_w      = (const float*)d_in[5];
    // d_in[6] = lin_b: unused — training-mode BN cancels per-channel shifts
    const float* gamma      = (const float*)d_in[7];
    const float* beta       = (const float*)d_in[8];

    float* out = (float*)d_out;

    // workspace layout (bytes): [0,128K) bfrag bf16; then 512 floats of
    // partial sums; then 128 floats of (a,b) affine params.
    unsigned short* bfrag = (unsigned short*)d_ws;
    float* part = (float*)d_ws + 32768;
    float* ab   = part + 512;

    const size_t xyz_elems = (size_t)BB * NN * 3;  // output 0 passthrough
    (void)hipMemcpyAsync(out, xyz, xyz_elems * sizeof(float),
                         hipMemcpyDeviceToDevice, stream);

    float* y_out = out + xyz_elems;  // [B][C][N]

    prep_bfrag<<<32, 256, 0, stream>>>(lin_w, bfrag);
    fused_main<<<BB * (NN / NT), 256, 0, stream>>>(
        points, coordinate, w1, b1, bfrag, y_out);
    bn_reduce<<<BB * CC, 256, 0, stream>>>(y_out, part);
    bn_stats<<<1, 64, 0, stream>>>(part, gamma, beta, ab);
    bn_apply<<<(BB * CC * NN) / 4 / 256, 256, 0, stream>>>(y_out, ab);
}

// Round 5
// 407.526 us; speedup vs baseline: 3.1761x; 1.1255x over previous
//
#include <hip/hip_runtime.h>

// Problem constants (fixed by setup_inputs)
#define BB 4
#define CC 64      // feature channels
#define KK 16      // neighbors
#define NN 16384   // points
#define NTB 128    // points per block = 2 independent 64-point pairs

typedef __attribute__((ext_vector_type(8))) short short8;     // 8 bf16 (MFMA A/B)
typedef __attribute__((ext_vector_type(4))) float floatx4;    // MFMA C/D
typedef __attribute__((ext_vector_type(2))) _Float16 half2v;  // packed f16 pair

__device__ __forceinline__ unsigned short f2bf_rtne(float x) {  // RTNE f32->bf16
    unsigned u = __builtin_bit_cast(unsigned, x);
    u += 0x7FFFu + ((u >> 16) & 1u);
    return (unsigned short)(u >> 16);
}

// pack two f32 into bf16x2 (round-half-up via +0x8000, then v_perm byte-select)
__device__ __forceinline__ unsigned pack_bf16x2(float lo, float hi) {
    unsigned a = __builtin_bit_cast(unsigned, lo) + 0x8000u;
    unsigned b = __builtin_bit_cast(unsigned, hi) + 0x8000u;
    return __builtin_amdgcn_perm(b, a, 0x07060302u);  // {b.hi16, a.hi16}
}

// cvt_pkrtz returns __fp16x2; bit_cast to _Float16x2 for fdot2
__device__ __forceinline__ half2v cvt2h(float a, float b) {
    return __builtin_bit_cast(half2v, __builtin_amdgcn_cvt_pkrtz(a, b));
}

#if __has_builtin(__builtin_amdgcn_fdot2)
#define DOT2(a, b, c) __builtin_amdgcn_fdot2((a), (b), (c), false)
#else
__device__ __forceinline__ float dot2_fb(half2v a, half2v b, float c) {
    return fmaf((float)a[0], (float)b[0], fmaf((float)a[1], (float)b[1], c));
}
#define DOT2(a, b, c) dot2_fb((a), (b), (c))
#endif

// ---------------------------------------------------------------------------
// One-time: repack lin_w (f32 [64][1024]) into bf16 MFMA B-fragments in the
// exact per-wave load order: [chunk ci][kk][nt][lane]{8 bf16}. 128 KB, L2-hot.
// ---------------------------------------------------------------------------
__global__ __launch_bounds__(256)
void prep_bfrag(const float* __restrict__ lin_w, unsigned short* __restrict__ bfrag)
{
    const int tid  = blockIdx.x * 256 + threadIdx.x;  // 0..8191
    const int lane = tid & 63;
    const int g    = tid >> 6;            // 0..127 = (ci,kk,nt)
    const int ci   = g >> 4;
    const int kk   = (g >> 2) & 3;
    const int nt   = g & 3;
    const int r    = lane & 15;
    const int sq   = lane >> 4;

    const float* src = lin_w + (size_t)(nt * 16 + r) * 1024 + ci * 128 + kk * 32 + sq * 8;
    unsigned short v[8];
    #pragma unroll
    for (int j = 0; j < 8; ++j) v[j] = f2bf_rtne(src[j]);
    *(uint4*)(bfrag + ((size_t)g * 64 + lane) * 8) = *(const uint4*)v;
}

// ---------------------------------------------------------------------------
// Fused weightnet + aggregation + linear(MFMA).
// Block = 256 thr = 4 waves = 2 independent 64-point PAIRS.
// Pair P = waves {2P, 2P+1}; within a pair, wave h computes weightnet/agg for
// o in [8h, 8h+8) (2x read redundancy instead of round-4's 4x).
// s_a holds agg in A-FRAGMENT-NATIVE layout [Mt][kk][r][sq] (uint4 chunks,
// Mt stride 257 = 256+1 pad -> both ds_write_b128 and ds_read_b128 spread
// 8 lanes per 4-bank group = conflict-free). Double-buffered per pair so the
// chunk loop needs ONE barrier, emitted as raw lgkmcnt(0)+s_barrier: vmcnt
// is NOT drained, so the distance-4 points prefetch pipeline and pre-barrier
// B-fragment loads stay in flight across barriers.
// lin_b dropped: training-mode BN cancels per-channel shifts.
// ---------------------------------------------------------------------------
__global__ __launch_bounds__(256, 2)
void fused_main(const float* __restrict__ points,
                const float* __restrict__ coordinate,
                const float* __restrict__ w1,
                const float* __restrict__ b1,
                const unsigned short* __restrict__ bfrag,
                float* __restrict__ y_out)   // [B][C][N] pre-BN
{
    __shared__ uint4 s_a[2][2][4 * 257];  // [pair][buf][Mt*257 + kk*64 + r*4 + sq]

    const int t    = threadIdx.x;
    const int lane = t & 63;
    const int wv   = __builtin_amdgcn_readfirstlane(t >> 6);
    const int P    = wv >> 1;      // pair id
    const int h    = wv & 1;       // o-half within pair
    const int r    = lane & 15;
    const int sq   = lane >> 4;

    const int bid = blockIdx.x;
    const int b   = bid >> 7;                    // 128 blocks per batch
    const int n0  = (bid & 127) * NTB + P * 64;  // pair's point base in batch

    // ---- weightnet into f16-pair registers: wh[j][kp], o = 8h + j
    half2v wh[8][8];
    {
        const float* coordB = coordinate + (size_t)b * 3 * KK * NN + n0 + lane;
        float c0[KK], c1[KK], c2[KK];
        #pragma unroll
        for (int k = 0; k < KK; ++k) {
            c0[k] = coordB[(0 * KK + k) * NN];
            c1[k] = coordB[(1 * KK + k) * NN];
            c2[k] = coordB[(2 * KK + k) * NN];
        }
        #pragma unroll
        for (int j = 0; j < 8; ++j) {
            const int o = 8 * h + j;
            const float w1x = w1[o * 3 + 0];
            const float w1y = w1[o * 3 + 1];
            const float w1z = w1[o * 3 + 2];
            const float bo  = b1[o];
            #pragma unroll
            for (int kp = 0; kp < 8; ++kp) {
                float v0 = fmaf(w1x, c0[2 * kp],     fmaf(w1y, c1[2 * kp],     fmaf(w1z, c2[2 * kp],     bo)));
                float v1 = fmaf(w1x, c0[2 * kp + 1], fmaf(w1y, c1[2 * kp + 1], fmaf(w1z, c2[2 * kp + 1], bo)));
                wh[j][kp] = cvt2h(fmaxf(v0, 0.0f), fmaxf(v1, 0.0f));
            }
        }
    }

    floatx4 acc[2][4];
    #pragma unroll
    for (int m = 0; m < 2; ++m)
        #pragma unroll
        for (int nt = 0; nt < 4; ++nt) acc[m][nt] = (floatx4){0.f, 0.f, 0.f, 0.f};

    const float* pB = points + (size_t)b * CC * KK * NN + n0 + lane;  // lane's column

    // ---- prime the distance-4 points pipeline (channels 0..3)
    float pv[4][16];
    #pragma unroll
    for (int d = 0; d < 4; ++d)
        #pragma unroll
        for (int k = 0; k < KK; ++k)
            pv[d][k] = pB[((size_t)d * KK + k) * NN];

    for (int ci = 0; ci < 8; ++ci) {
        const int buf = ci & 1;
        uint4* saW = &s_a[P][buf][0];
        #pragma unroll
        for (int cl = 0; cl < 8; ++cl) {
            const int cc   = ci * 8 + cl;
            const int slot = cc & 3;
            // consume slot -> packed f16
            half2v ph[8];
            #pragma unroll
            for (int kp = 0; kp < 8; ++kp)
                ph[kp] = cvt2h(pv[slot][2 * kp], pv[slot][2 * kp + 1]);
            // refill slot with channel cc+4 (clamped; tail loads are dead)
            {
                const int cp = (cc + 4 < CC) ? (cc + 4) : (CC - 1);
                #pragma unroll
                for (int k = 0; k < KK; ++k)
                    pv[slot][k] = pB[((size_t)cp * KK + k) * NN];
            }
            // 8-o dot over 16 k
            float a8[8];
            #pragma unroll
            for (int j = 0; j < 8; ++j) {
                float a = 0.f;
                #pragma unroll
                for (int kp = 0; kp < 8; ++kp) a = DOT2(ph[kp], wh[j][kp], a);
                a8[j] = a;
            }
            uint4 pk;
            pk.x = pack_bf16x2(a8[0], a8[1]);
            pk.y = pack_bf16x2(a8[2], a8[3]);
            pk.z = pack_bf16x2(a8[4], a8[5]);
            pk.w = pack_bf16x2(a8[6], a8[7]);
            // A-frag-native store: n=lane -> Mt=lane>>4, r=lane&15;
            // k' = cl*16+8h -> kk=cl>>1, sq=(cl&1)*2+h
            saW[(lane >> 4) * 257 + (cl >> 1) * 64 + (lane & 15) * 4 + (cl & 1) * 2 + h] = pk;
        }

        // B-frags kk=0 issued BEFORE the barrier (stay in flight across it)
        uint4 bf_c[4];
        #pragma unroll
        for (int nt = 0; nt < 4; ++nt)
            bf_c[nt] = *(const uint4*)(bfrag + ((((size_t)ci * 4 + 0) * 4 + nt) * 64 + lane) * 8);

        // LDS-only barrier: lgkmcnt(0) for s_a visibility, NO vmcnt drain
        asm volatile("s_waitcnt lgkmcnt(0)\n\ts_barrier" ::: "memory");

        const uint4* saR = &s_a[P][buf][0];
        #pragma unroll
        for (int kk = 0; kk < 4; ++kk) {
            uint4 bf_n[4];
            if (kk < 3) {
                #pragma unroll
                for (int nt = 0; nt < 4; ++nt)
                    bf_n[nt] = *(const uint4*)(bfrag + ((((size_t)ci * 4 + kk + 1) * 4 + nt) * 64 + lane) * 8);
            }
            short8 af[2];
            #pragma unroll
            for (int m = 0; m < 2; ++m)
                af[m] = __builtin_bit_cast(short8, saR[(2 * h + m) * 257 + kk * 64 + r * 4 + sq]);
            #pragma unroll
            for (int m = 0; m < 2; ++m)
                #pragma unroll
                for (int nt = 0; nt < 4; ++nt)
                    acc[m][nt] = __builtin_amdgcn_mfma_f32_16x16x32_bf16(
                        af[m], __builtin_bit_cast(short8, bf_c[nt]), acc[m][nt], 0, 0, 0);
            #pragma unroll
            for (int nt = 0; nt < 4; ++nt) bf_c[nt] = bf_n[nt];
        }
    }

    // ---- epilogue: D col=lane&15 (oc), row=quad*4+reg (point within tile)
    float* yB = y_out + (size_t)b * CC * NN + n0;
    #pragma unroll
    for (int m = 0; m < 2; ++m)
        #pragma unroll
        for (int nt = 0; nt < 4; ++nt) {
            const int oc = nt * 16 + r;
            const float4 v = make_float4(acc[m][nt][0], acc[m][nt][1],
                                         acc[m][nt][2], acc[m][nt][3]);
            *(float4*)(yB + (size_t)oc * NN + (2 * h + m) * 16 + sq * 4) = v;
        }
}

// ---------------------------------------------------------------------------
// Partial batch stats: one block per (b, ch); deterministic.
// ---------------------------------------------------------------------------
__global__ __launch_bounds__(256)
void bn_reduce(const float* __restrict__ y, float* __restrict__ part)
{
    const int ch = blockIdx.x & 63;
    const int b  = blockIdx.x >> 6;
    const int t  = threadIdx.x;
    const float4* p = (const float4*)(y + ((size_t)b * CC + ch) * NN);
    float s = 0.f, ss = 0.f;
    for (int i = t; i < NN / 4; i += 256) {
        const float4 v = p[i];
        s  += v.x + v.y + v.z + v.w;
        ss += v.x * v.x + v.y * v.y + v.z * v.z + v.w * v.w;
    }
    #pragma unroll
    for (int m = 1; m < 64; m <<= 1) {
        s  += __shfl_xor(s, m);
        ss += __shfl_xor(ss, m);
    }
    __shared__ float rs[4], rss[4];
    if ((t & 63) == 0) { rs[t >> 6] = s; rss[t >> 6] = ss; }
    __syncthreads();
    if (t == 0) {
        part[blockIdx.x]       = rs[0] + rs[1] + rs[2] + rs[3];
        part[256 + blockIdx.x] = rss[0] + rss[1] + rss[2] + rss[3];
    }
}

__global__ void bn_stats(const float* __restrict__ part,
                         const float* __restrict__ gamma,
                         const float* __restrict__ beta,
                         float* __restrict__ ab)
{
    const int ch = threadIdx.x;
    float S = 0.f, SS = 0.f;
    #pragma unroll
    for (int b = 0; b < BB; ++b) {
        S  += part[b * 64 + ch];
        SS += part[256 + b * 64 + ch];
    }
    const float inv  = 1.0f / (float)(BB * NN);
    const float mean = S * inv;
    const float var  = SS * inv - mean * mean;
    const float a    = gamma[ch] * rsqrtf(var + 1e-5f);
    ab[ch]      = a;
    ab[CC + ch] = beta[ch] - mean * a;
}

__global__ __launch_bounds__(256)
void bn_apply(float* __restrict__ y, const float* __restrict__ ab)
{
    const size_t i = (size_t)blockIdx.x * 256 + threadIdx.x;  // float4 index
    float4* p = (float4*)y;
    float4 v = p[i];
    const int ch = (int)((i * 4) >> 14) & 63;  // (elem / N) % C
    const float a = ab[ch], bb = ab[CC + ch];
    v.x = fmaxf(fmaf(a, v.x, bb), 0.0f);
    v.y = fmaxf(fmaf(a, v.y, bb), 0.0f);
    v.z = fmaxf(fmaf(a, v.z, bb), 0.0f);
    v.w = fmaxf(fmaf(a, v.w, bb), 0.0f);
    p[i] = v;
}

extern "C" void kernel_launch(void* const* d_in, const int* in_sizes, int n_in,
                              void* d_out, int out_size, void* d_ws, size_t ws_size,
                              hipStream_t stream)
{
    const float* xyz        = (const float*)d_in[0];
    const float* points     = (const float*)d_in[1];
    const float* coordinate = (const float*)d_in[2];
    const float* w1         = (const float*)d_in[3];
    const float* b1         = (const float*)d_in[4];
    const float* lin_w      = (const float*)d_in[5];
    // d_in[6] = lin_b: unused — training-mode BN cancels per-channel shifts
    const float* gamma      = (const float*)d_in[7];
    const float* beta       = (const float*)d_in[8];

    float* out = (float*)d_out;

    // workspace: [0,128K) bfrag bf16; then 512 floats partials; then 128 ab
    unsigned short* bfrag = (unsigned short*)d_ws;
    float* part = (float*)d_ws + 32768;
    float* ab   = part + 512;

    const size_t xyz_elems = (size_t)BB * NN * 3;  // output 0 passthrough
    (void)hipMemcpyAsync(out, xyz, xyz_elems * sizeof(float),
                         hipMemcpyDeviceToDevice, stream);

    float* y_out = out + xyz_elems;  // [B][C][N]

    prep_bfrag<<<32, 256, 0, stream>>>(lin_w, bfrag);
    fused_main<<<BB * (NN / NTB), 256, 0, stream>>>(
        points, coordinate, w1, b1, bfrag, y_out);
    bn_reduce<<<BB * CC, 256, 0, stream>>>(y_out, part);
    bn_stats<<<1, 64, 0, stream>>>(part, gamma, beta, ab);
    bn_apply<<<(BB * CC * NN) / 4 / 256, 256, 0, stream>>>(y_out, ab);
}